// Round 4
// baseline (187.386 us; speedup 1.0000x reference)
//
#include <hip/hip_runtime.h>
#include <stdint.h>

// ---------------------------------------------------------------------------
// LinearBlock: out[b, p*8+o] = clip((sum_{q,i} Wq[p,q,o,i]*xq[b,q*8+i])^2, 0, 6)
// Exact int8 path:
//   xq = xu/255,        xu = round(clip(x,0,1)*255)       in [0,255]
//   wq = wi*2/127,      wi = round(clip(w,-2,2)*63.5)     in [-127,127]
//   dot = (sum xu*wi) * 2/(255*127);  A zero-point: xs=xu-128, +128*rowsum[n].
//
// Round 4: quant_x FUSED into GEMM (A reg-staged f32->quant->ds_write, late;
// B via global_load_lds). One barrier per K-tile; counted lgkmcnt(2)
// interleave of ds_reads with 4-MFMA clusters; counted vmcnt(2) (never 0 in
// main loop); 3-buffer LDS ring; XOR chunk swizzle both-sides; XCD swizzle.
// ---------------------------------------------------------------------------

typedef int i32x4 __attribute__((ext_vector_type(4)));

#define B_DIM   16384
#define IN_DIM  2048
#define OUT_DIM 2048

#define BM 256
#define BN 256
#define BK 64
#define KTILES (IN_DIM / BK)   // 32
#define ATILE  (BM * BK)       // 16384 bytes
#define BUFB   (2 * ATILE)     // 32768 bytes (A half + B half)

__device__ __forceinline__ void async16(const void* g, void* l) {
    __builtin_amdgcn_global_load_lds(
        (const __attribute__((address_space(1))) void*)g,
        (__attribute__((address_space(3))) void*)l, 16, 0, 0);
}

__device__ __forceinline__ int q4(float4 v) {
    // exact same math as the reference: round(clip(x,0,1)*255) - 128
    int a = (int)rintf(fminf(fmaxf(v.x, 0.f), 1.f) * 255.f) - 128;
    int b = (int)rintf(fminf(fmaxf(v.y, 0.f), 1.f) * 255.f) - 128;
    int c = (int)rintf(fminf(fmaxf(v.z, 0.f), 1.f) * 255.f) - 128;
    int d = (int)rintf(fminf(fmaxf(v.w, 0.f), 1.f) * 255.f) - 128;
    return (a & 255) | ((b & 255) << 8) | ((c & 255) << 16) | ((d & 255) << 24);
}

// --- quantize + relayout weight: [P=256,Q=256,8,8] f32 -> [2048][2048] int8
__global__ __launch_bounds__(256) void quant_w_kernel(const float* __restrict__ w,
                                                      int8_t* __restrict__ wq,
                                                      int* __restrict__ rowsum) {
    int p = blockIdx.x;          // 0..255
    int t = threadIdx.x;         // 0..255
    const float* wp = w + (size_t)p * 16384;
    int n = p * 8 + (t & 7);
    int lsum = 0;
#pragma unroll
    for (int s = 0; s < 8; ++s) {
        int g = t + s * 256;                     // 8-elem group id, 0..2047
        float4 v0 = *(const float4*)(wp + g * 8);
        float4 v1 = *(const float4*)(wp + g * 8 + 4);
        float f[8] = {v0.x, v0.y, v0.z, v0.w, v1.x, v1.y, v1.z, v1.w};
        union { int8_t c[8]; long long ll; } u;
#pragma unroll
        for (int e = 0; e < 8; ++e) {
            float c = fminf(fmaxf(f[e], -2.0f), 2.0f);
            int q = (int)rintf(c * 63.5f);       // == round((w/2)*127), exact
            u.c[e] = (int8_t)q;
            lsum += q;
        }
        int kg = g >> 3;
        *(long long*)(wq + (size_t)n * 2048 + kg * 8) = u.ll;
    }
    atomicAdd(&rowsum[n], lsum);
}

#define SB0 __builtin_amdgcn_sched_barrier(0)
#define WLG(n) asm volatile("s_waitcnt lgkmcnt(" #n ")" ::: "memory")
#define WVM(n) asm volatile("s_waitcnt vmcnt(" #n ")" ::: "memory")

#define CL(mm)                                                                \
    _Pragma("unroll")                                                         \
    for (int n = 0; n < 4; ++n)                                               \
        acc[mm][n] = __builtin_amdgcn_mfma_i32_16x16x64_i8(af[mm], bf[n],     \
                                                           acc[mm][n], 0, 0, 0);

// One K-tile on buffer BI; stages tile KT2 into buffer (BI+2)%3 when STG.
// TAILW: 2 = steady state (vmcnt(2) before A ds_write); 0 = drain tile
// (vmcnt(0), no stage); -1 = last tile (no vmem wait).
#define DO_TILE(BI, KT2, STG, TAILW) do {                                     \
    const int8_t* la = lds + (BI) * BUFB;                                     \
    const int8_t* lb = la + ATILE;                                            \
    int8_t* dst = lds + (((BI) + 2) % 3) * BUFB;                              \
    if (STG) {  /* issue A f32 loads for tile KT2 (consumed late) */          \
        const float* g0 = gx0 + (size_t)(KT2) * BK;                           \
        const float* g1 = gx1 + (size_t)(KT2) * BK;                           \
        fa0 = *(const float4*)(g0);       fa1 = *(const float4*)(g0 + 4);     \
        fa2 = *(const float4*)(g0 + 8);   fa3 = *(const float4*)(g0 + 12);    \
        fa4 = *(const float4*)(g1);       fa5 = *(const float4*)(g1 + 4);     \
        fa6 = *(const float4*)(g1 + 8);   fa7 = *(const float4*)(g1 + 12);    \
    }                                                                         \
    SB0;                                                                      \
    if (STG) {  /* B via DMA, issued after A (vmcnt(2) => A done) */          \
        async16(gB0 + (KT2) * BK, dst + ATILE + ldsOff);                      \
        async16(gB1 + (KT2) * BK, dst + ATILE + ldsOff + 8192);               \
    }                                                                         \
    SB0;                                                                      \
    bf[0] = *(const i32x4*)(lb + boff);                                       \
    bf[1] = *(const i32x4*)(lb + boff + 1024);                                \
    bf[2] = *(const i32x4*)(lb + boff + 2048);                                \
    bf[3] = *(const i32x4*)(lb + boff + 3072);                                \
    af[0] = *(const i32x4*)(la + aoff);                                       \
    SB0;                                                                      \
    af[1] = *(const i32x4*)(la + aoff + 1024);                                \
    af[2] = *(const i32x4*)(la + aoff + 2048);                                \
    SB0;                                                                      \
    __builtin_amdgcn_s_setprio(1);                                            \
    WLG(2); SB0; CL(0);                                                       \
    af[3] = *(const i32x4*)(la + aoff + 3072); SB0;                           \
    WLG(2); SB0; CL(1);                                                       \
    af[4] = *(const i32x4*)(la + aoff + 4096); SB0;                           \
    WLG(2); SB0; CL(2);                                                       \
    af[5] = *(const i32x4*)(la + aoff + 5120); SB0;                           \
    WLG(2); SB0; CL(3);                                                       \
    af[6] = *(const i32x4*)(la + aoff + 6144); SB0;                           \
    WLG(2); SB0; CL(4);                                                       \
    af[7] = *(const i32x4*)(la + aoff + 7168); SB0;                           \
    WLG(2); SB0; CL(5);                                                       \
    WLG(1); SB0; CL(6);                                                       \
    WLG(0); SB0; CL(7);                                                       \
    __builtin_amdgcn_s_setprio(0);                                            \
    SB0;                                                                      \
    if (STG) {  /* late: quantize A(KT2) and write into dst (T14) */          \
        WVM(2); SB0;                                                          \
        i32x4 pk0, pk1;                                                       \
        pk0[0] = q4(fa0); pk0[1] = q4(fa1); pk0[2] = q4(fa2); pk0[3] = q4(fa3);\
        pk1[0] = q4(fa4); pk1[1] = q4(fa5); pk1[2] = q4(fa6); pk1[3] = q4(fa7);\
        *(i32x4*)(dst + ldsOff) = pk0;                                        \
        *(i32x4*)(dst + ldsOff + 8192) = pk1;                                 \
    }                                                                         \
    if ((TAILW) == 0) { WVM(0); }                                             \
    WLG(0);                                                                   \
    __builtin_amdgcn_s_barrier();                                             \
} while (0)

// --- fused quantize-A + int8 GEMM: 256x256 tile, 8 waves, 3-buffer ring ---
__global__ __launch_bounds__(512, 2) void gemm_i8_kernel(const float* __restrict__ X,
                                                         const int8_t* __restrict__ W,
                                                         const int* __restrict__ rowsum,
                                                         float* __restrict__ out) {
    extern __shared__ int8_t lds[];   // 3 * 32 KB

    // XCD-aware swizzle: 512 wgs, 8 XCDs, 64 contiguous tiles per XCD
    int bid = blockIdx.x;
    int wg = (bid & 7) * 64 + (bid >> 3);
    int tm = wg >> 3;                 // 64 row tiles
    int tn = wg & 7;                  // 8 col tiles
    int brow = tm * BM;
    int bcol = tn * BN;

    int tid  = threadIdx.x;
    int lane = tid & 63;
    int wv   = tid >> 6;
    int wr = wv >> 2, wc = wv & 3;    // 2x4 waves, each 128x64 output
    int l15 = lane & 15;
    int kg  = lane >> 4;              // 0..3

    // staging: thread owns rows r0, r0+128; LDS chunk (r,c) holds global
    // chunk (r, c ^ ((r>>1)&3)); sw is an element offset (i8 and f32 alike).
    int r0 = tid >> 2;                // 0..127
    int c0 = tid & 3;
    int sw = ((c0 ^ ((r0 >> 1) & 3)) << 4);
    const float*  gx0 = X + (size_t)(brow + r0) * IN_DIM + sw;
    const float*  gx1 = X + (size_t)(brow + r0 + 128) * IN_DIM + sw;
    const int8_t* gB0 = W + (size_t)(bcol + r0) * IN_DIM + sw;
    const int8_t* gB1 = W + (size_t)(bcol + r0 + 128) * IN_DIM + sw;
    const int ldsOff = tid * 16;

    // ds_read: lane wants (row, k-chunk kg); swizzled chunk index is
    // kg ^ ((row>>1)&3), and (row>>1)&3 == (l15>>1)&3 for all fragments.
    const int koff = ((kg ^ ((l15 >> 1) & 3)) << 4);
    const int aoff = (wr * 128 + l15) * BK + koff;    // + m*1024
    const int boff = (wc * 64 + l15) * BK + koff;     // + n*1024

    i32x4 acc[8][4];
#pragma unroll
    for (int m = 0; m < 8; ++m)
#pragma unroll
        for (int n = 0; n < 4; ++n)
            acc[m][n] = (i32x4){0, 0, 0, 0};
    i32x4 af[8], bf[4];
    float4 fa0, fa1, fa2, fa3, fa4, fa5, fa6, fa7;

    // ---- prologue: tiles 0,1 into buf0,buf1 ----
    fa0 = *(const float4*)(gx0);      fa1 = *(const float4*)(gx0 + 4);
    fa2 = *(const float4*)(gx0 + 8);  fa3 = *(const float4*)(gx0 + 12);
    fa4 = *(const float4*)(gx1);      fa5 = *(const float4*)(gx1 + 4);
    fa6 = *(const float4*)(gx1 + 8);  fa7 = *(const float4*)(gx1 + 12);
    SB0;
    async16(gB0, lds + ATILE + ldsOff);
    async16(gB1, lds + ATILE + ldsOff + 8192);
    async16(gB0 + BK, lds + BUFB + ATILE + ldsOff);
    async16(gB1 + BK, lds + BUFB + ATILE + ldsOff + 8192);
    SB0;
    WVM(4); SB0;                       // A(t0) landed; 4 B-DMAs in flight
    {
        i32x4 pk0, pk1;
        pk0[0] = q4(fa0); pk0[1] = q4(fa1); pk0[2] = q4(fa2); pk0[3] = q4(fa3);
        pk1[0] = q4(fa4); pk1[1] = q4(fa5); pk1[2] = q4(fa6); pk1[3] = q4(fa7);
        *(i32x4*)(lds + ldsOff) = pk0;
        *(i32x4*)(lds + ldsOff + 8192) = pk1;
    }
    fa0 = *(const float4*)(gx0 + BK);      fa1 = *(const float4*)(gx0 + BK + 4);
    fa2 = *(const float4*)(gx0 + BK + 8);  fa3 = *(const float4*)(gx0 + BK + 12);
    fa4 = *(const float4*)(gx1 + BK);      fa5 = *(const float4*)(gx1 + BK + 4);
    fa6 = *(const float4*)(gx1 + BK + 8);  fa7 = *(const float4*)(gx1 + BK + 12);
    SB0;
    WVM(0); SB0;                       // A(t1) + all B landed
    {
        i32x4 pk0, pk1;
        pk0[0] = q4(fa0); pk0[1] = q4(fa1); pk0[2] = q4(fa2); pk0[3] = q4(fa3);
        pk1[0] = q4(fa4); pk1[1] = q4(fa5); pk1[2] = q4(fa6); pk1[3] = q4(fa7);
        *(i32x4*)(lds + BUFB + ldsOff) = pk0;
        *(i32x4*)(lds + BUFB + ldsOff + 8192) = pk1;
    }
    WLG(0);
    __builtin_amdgcn_s_barrier();

    // ---- main loop: tiles 0..29 stage tiles 2..31; then 2 tail tiles ----
    int kt = 0;
#pragma unroll 1
    for (int t = 0; t < 10; ++t) {
        DO_TILE(0, kt + 2, 1, 2);
        DO_TILE(1, kt + 3, 1, 2);
        DO_TILE(2, kt + 4, 1, 2);
        kt += 3;
    }
    DO_TILE(0, 0, 0, 0);    // tile 30: drain tile 31's B-DMAs
    DO_TILE(1, 0, 0, -1);   // tile 31

    // ---- epilogue: zero-point, scale, photodetect square, ReLUN(6) ----
    const float scale = (float)(2.0 / 32385.0);   // 2/(255*127)
#pragma unroll
    for (int n = 0; n < 4; ++n) {
        int col = bcol + wc * 64 + n * 16 + l15;
        int rs128 = rowsum[col] << 7;             // 128 * sum_k wi[col,k]
#pragma unroll
        for (int m = 0; m < 8; ++m) {
            int row0 = brow + wr * 128 + m * 16 + kg * 4;
#pragma unroll
            for (int r = 0; r < 4; ++r) {
                float f = (float)(acc[m][n][r] + rs128) * scale;
                f = f * f;
                f = fminf(f, 6.0f);
                out[(size_t)(row0 + r) * OUT_DIM + col] = f;
            }
        }
    }
}

extern "C" void kernel_launch(void* const* d_in, const int* in_sizes, int n_in,
                              void* d_out, int out_size, void* d_ws, size_t ws_size,
                              hipStream_t stream) {
    const float* x  = (const float*)d_in[0];   // [16384, 2048] f32
    const float* wt = (const float*)d_in[1];   // [256, 256, 8, 8] f32
    float* out = (float*)d_out;                // [16384, 2048] f32

    char* ws = (char*)d_ws;
    int8_t* wq = (int8_t*)ws;                                   // 4 MB
    int*    rowsum = (int*)(ws + (size_t)OUT_DIM * IN_DIM);     // 8 KB

    hipMemsetAsync(rowsum, 0, OUT_DIM * sizeof(int), stream);
    quant_w_kernel<<<256, 256, 0, stream>>>(wt, wq, rowsum);
    gemm_i8_kernel<<<(B_DIM / BM) * (OUT_DIM / BN), 512, 3 * BUFB, stream>>>(x, wq, rowsum, out);
}

// Round 5
// 121.686 us; speedup vs baseline: 1.5399x; 1.5399x over previous
//
#include <hip/hip_runtime.h>
#include <stdint.h>

// ---------------------------------------------------------------------------
// LinearBlock: out[b, p*8+o] = clip((sum_{q,i} Wq[p,q,o,i]*xq[b,q*8+i])^2, 0, 6)
// Exact int8 path:
//   xq = xu/255,        xu = round(clip(x,0,1)*255)       in [0,255]
//   wq = wi*2/127,      wi = round(clip(w,-2,2)*63.5)     in [-127,127]
//   dot = (sum xu*wi) * 2/(255*127);  A zero-point: xs=xu-128, +128*rowsum[n].
//
// Round 5: separate quant kernels (round-3 pipeline, reverting round-4 fusion).
// GEMM: 256x256 tile, BK=128 (i8 == m201's bf16 byte geometry), 8 waves
// (2Mx4N), double-buffered 128 KB LDS, 4 phases per K-tile, each phase
// {ds_reads, 2 gload_lds, barrier, lgkmcnt(0), setprio(1), 16 MFMA,
// setprio(0), barrier}; single vmcnt(0) at tile end (loads issued >=2 phases
// earlier). XOR chunk swizzle (c ^= (row>>1)&7) both-sides; XCD block swizzle.
// ---------------------------------------------------------------------------

typedef int i32x4 __attribute__((ext_vector_type(4)));

#define B_DIM   16384
#define IN_DIM  2048
#define OUT_DIM 2048

#define BM 256
#define BN 256
#define BK 128
#define KTILES (IN_DIM / BK)   // 16
#define ATILE  (BM * BK)       // 32768 bytes
#define BUFB   (2 * ATILE)     // 65536 bytes (A half + B half)

__device__ __forceinline__ void async16(const void* g, void* l) {
    __builtin_amdgcn_global_load_lds(
        (const __attribute__((address_space(1))) void*)g,
        (__attribute__((address_space(3))) void*)l, 16, 0, 0);
}

// --- quantize x: float [B,IN] -> int8 (value-128) [B,IN], 16 elems/thread ---
__global__ __launch_bounds__(256) void quant_x_kernel(const float* __restrict__ x,
                                                      int8_t* __restrict__ xq) {
    int i = blockIdx.x * 256 + threadIdx.x;           // 16-elem chunk id
    const float4* xv = (const float4*)x + (size_t)i * 4;
    union { int8_t c[16]; i32x4 v; } u;
#pragma unroll
    for (int j = 0; j < 4; ++j) {
        float4 v = xv[j];
        float f[4] = {v.x, v.y, v.z, v.w};
#pragma unroll
        for (int e = 0; e < 4; ++e) {
            float c = fminf(fmaxf(f[e], 0.0f), 1.0f);
            int q = (int)rintf(c * 255.0f) - 128;
            u.c[j * 4 + e] = (int8_t)q;
        }
    }
    *((i32x4*)xq + i) = u.v;
}

// --- quantize + relayout weight: [P=256,Q=256,8,8] f32 -> [2048][2048] int8
__global__ __launch_bounds__(256) void quant_w_kernel(const float* __restrict__ w,
                                                      int8_t* __restrict__ wq,
                                                      int* __restrict__ rowsum) {
    int p = blockIdx.x;          // 0..255
    int t = threadIdx.x;         // 0..255
    const float* wp = w + (size_t)p * 16384;
    int n = p * 8 + (t & 7);
    int lsum = 0;
#pragma unroll
    for (int s = 0; s < 8; ++s) {
        int g = t + s * 256;                     // 8-elem group id, 0..2047
        float4 v0 = *(const float4*)(wp + g * 8);
        float4 v1 = *(const float4*)(wp + g * 8 + 4);
        float f[8] = {v0.x, v0.y, v0.z, v0.w, v1.x, v1.y, v1.z, v1.w};
        union { int8_t c[8]; long long ll; } u;
#pragma unroll
        for (int e = 0; e < 8; ++e) {
            float c = fminf(fmaxf(f[e], -2.0f), 2.0f);
            int q = (int)rintf(c * 63.5f);       // == round((w/2)*127), exact
            u.c[e] = (int8_t)q;
            lsum += q;
        }
        int kg = g >> 3;
        *(long long*)(wq + (size_t)n * 2048 + kg * 8) = u.ll;
    }
    atomicAdd(&rowsum[n], lsum);
}

#define SB0 __builtin_amdgcn_sched_barrier(0)
#define BAR __builtin_amdgcn_s_barrier()
#define WLG0 asm volatile("s_waitcnt lgkmcnt(0)" ::: "memory")
#define WVM0 asm volatile("s_waitcnt vmcnt(0)" ::: "memory")

#define CL(mm)                                                                \
    _Pragma("unroll")                                                         \
    for (int n = 0; n < 4; ++n)                                               \
        acc[mm][n] = __builtin_amdgcn_mfma_i32_16x16x64_i8(af[mm], bf[n],     \
                                                           acc[mm][n], 0, 0, 0);

// One K-tile on buffer BI; when STG, stages tile KT2 into buffer BI^1.
// 4 phases x 16 MFMA, m201 anatomy. Loads: A in P0/P1, B in P2/P3.
#define DO_TILE(BI, KT2, STG) do {                                            \
    const int8_t* la = lds + (BI) * BUFB;                                     \
    const int8_t* lb = la + ATILE;                                            \
    int8_t* dst = lds + ((BI) ^ 1) * BUFB;                                    \
    const int kb = (KT2) * BK;                                                \
    /* ---- P0: m0-3 x kstep0 ---- */                                         \
    af[0] = *(const i32x4*)(la + aoff0);                                      \
    af[1] = *(const i32x4*)(la + aoff0 + 2048);                               \
    af[2] = *(const i32x4*)(la + aoff0 + 4096);                               \
    af[3] = *(const i32x4*)(la + aoff0 + 6144);                               \
    bf[0] = *(const i32x4*)(lb + boff0);                                      \
    bf[1] = *(const i32x4*)(lb + boff0 + 2048);                               \
    bf[2] = *(const i32x4*)(lb + boff0 + 4096);                               \
    bf[3] = *(const i32x4*)(lb + boff0 + 6144);                               \
    if (STG) { async16(gA + kb,          dst + ldsOff);                       \
               async16(gA + 131072 + kb, dst + 8192 + ldsOff); }              \
    SB0; BAR; WLG0; SB0;                                                      \
    __builtin_amdgcn_s_setprio(1);                                            \
    CL(0); CL(1); CL(2); CL(3);                                               \
    __builtin_amdgcn_s_setprio(0); SB0; BAR;                                  \
    /* ---- P1: m4-7 x kstep0 ---- */                                         \
    af[4] = *(const i32x4*)(la + aoff0 + 8192);                               \
    af[5] = *(const i32x4*)(la + aoff0 + 10240);                              \
    af[6] = *(const i32x4*)(la + aoff0 + 12288);                              \
    af[7] = *(const i32x4*)(la + aoff0 + 14336);                              \
    if (STG) { async16(gA + 262144 + kb, dst + 16384 + ldsOff);               \
               async16(gA + 393216 + kb, dst + 24576 + ldsOff); }             \
    SB0; BAR; WLG0; SB0;                                                      \
    __builtin_amdgcn_s_setprio(1);                                            \
    CL(4); CL(5); CL(6); CL(7);                                               \
    __builtin_amdgcn_s_setprio(0); SB0; BAR;                                  \
    /* ---- P2: m0-3 x kstep1 ---- */                                         \
    af[0] = *(const i32x4*)(la + aoff1);                                      \
    af[1] = *(const i32x4*)(la + aoff1 + 2048);                               \
    af[2] = *(const i32x4*)(la + aoff1 + 4096);                               \
    af[3] = *(const i32x4*)(la + aoff1 + 6144);                               \
    bf[0] = *(const i32x4*)(lb + boff1);                                      \
    bf[1] = *(const i32x4*)(lb + boff1 + 2048);                               \
    bf[2] = *(const i32x4*)(lb + boff1 + 4096);                               \
    bf[3] = *(const i32x4*)(lb + boff1 + 6144);                               \
    if (STG) { async16(gB + kb,          dst + ATILE + ldsOff);               \
               async16(gB + 131072 + kb, dst + ATILE + 8192 + ldsOff); }      \
    SB0; BAR; WLG0; SB0;                                                      \
    __builtin_amdgcn_s_setprio(1);                                            \
    CL(0); CL(1); CL(2); CL(3);                                               \
    __builtin_amdgcn_s_setprio(0); SB0; BAR;                                  \
    /* ---- P3: m4-7 x kstep1 ---- */                                         \
    af[4] = *(const i32x4*)(la + aoff1 + 8192);                               \
    af[5] = *(const i32x4*)(la + aoff1 + 10240);                              \
    af[6] = *(const i32x4*)(la + aoff1 + 12288);                              \
    af[7] = *(const i32x4*)(la + aoff1 + 14336);                              \
    if (STG) { async16(gB + 262144 + kb, dst + ATILE + 16384 + ldsOff);       \
               async16(gB + 393216 + kb, dst + ATILE + 24576 + ldsOff); }     \
    SB0; BAR; WLG0; SB0;                                                      \
    __builtin_amdgcn_s_setprio(1);                                            \
    CL(4); CL(5); CL(6); CL(7);                                               \
    __builtin_amdgcn_s_setprio(0); SB0;                                       \
    if (STG) { WVM0; }                                                        \
    BAR;                                                                      \
} while (0)

// --- int8 GEMM: 256x256 tile, BK=128, 8 waves, 2-buffer, 4-phase K-tiles ---
__global__ __launch_bounds__(512, 2) void gemm_i8_kernel(const int8_t* __restrict__ A,
                                                         const int8_t* __restrict__ W,
                                                         const int* __restrict__ rowsum,
                                                         float* __restrict__ out) {
    extern __shared__ int8_t lds[];   // 2 * 64 KB

    // XCD-aware swizzle: 512 wgs, 8 XCDs, 64 contiguous tiles per XCD
    int bid = blockIdx.x;
    int wg = (bid & 7) * 64 + (bid >> 3);
    int tm = wg >> 3;                 // 64 row tiles
    int tn = wg & 7;                  // 8 col tiles
    int brow = tm * BM;
    int bcol = tn * BN;

    int tid  = threadIdx.x;
    int lane = tid & 63;
    int wv   = tid >> 6;
    int wr = wv >> 2, wc = wv & 3;    // 2x4 waves, each 128x64 output
    int l15 = lane & 15;
    int kg  = lane >> 4;              // 0..3

    // staging: thread covers chunk (s*512 + tid) of each 32 KB half-tile,
    // i.e. row = s*64 + (tid>>3), chunk col = tid&7. LDS chunk (r,c) holds
    // global chunk (r, c ^ ((r>>1)&7)); ((r>>1)&7) == (tid>>4)&7 for all s.
    int t8  = tid >> 3;               // 0..63
    int csw = (tid & 7) ^ ((tid >> 4) & 7);
    const int8_t* gA = A + (size_t)(brow + t8) * IN_DIM + csw * 16;
    const int8_t* gB = W + (size_t)(bcol + t8) * IN_DIM + csw * 16;
    const int ldsOff = tid * 16;      // within each 8 KB (s) slice

    // ds_read: lane wants (row, chunk = ks*4 + kg); swizzled chunk index is
    // (ks*4+kg) ^ ((row>>1)&7), and (row>>1)&7 == (l15>>1)&7 for all frags.
    const int xsw   = (l15 >> 1) & 7;
    const int koff0 = ((kg ^ xsw) << 4);
    const int koff1 = (((4 + kg) ^ xsw) << 4);
    const int arp = (wr * 128 + l15) * BK;
    const int brp = (wc * 64 + l15) * BK;
    const int aoff0 = arp + koff0, aoff1 = arp + koff1;   // + m*16*BK (=2048)
    const int boff0 = brp + koff0, boff1 = brp + koff1;   // + n*16*BK

    i32x4 acc[8][4];
#pragma unroll
    for (int m = 0; m < 8; ++m)
#pragma unroll
        for (int n = 0; n < 4; ++n)
            acc[m][n] = (i32x4){0, 0, 0, 0};
    i32x4 af[8], bf[4];

    // ---- prologue: stage tile 0 into buf0, drain ----
    async16(gA,          lds + ldsOff);
    async16(gA + 131072, lds + 8192 + ldsOff);
    async16(gA + 262144, lds + 16384 + ldsOff);
    async16(gA + 393216, lds + 24576 + ldsOff);
    async16(gB,          lds + ATILE + ldsOff);
    async16(gB + 131072, lds + ATILE + 8192 + ldsOff);
    async16(gB + 262144, lds + ATILE + 16384 + ldsOff);
    async16(gB + 393216, lds + ATILE + 24576 + ldsOff);
    SB0; WVM0; BAR;

    // ---- main loop: 16 K-tiles; tile kt stages kt+1 into buf^1 ----
#pragma unroll 1
    for (int t = 0; t < 7; ++t) {
        int kt = 2 * t;
        DO_TILE(0, kt + 1, 1);
        DO_TILE(1, kt + 2, 1);
    }
    DO_TILE(0, 15, 1);
    DO_TILE(1, 0, 0);

    // ---- epilogue: zero-point, scale, photodetect square, ReLUN(6) ----
    const float scale = (float)(2.0 / 32385.0);   // 2/(255*127)
#pragma unroll
    for (int n = 0; n < 4; ++n) {
        int col = bcol + wc * 64 + n * 16 + l15;
        int rs128 = rowsum[col] << 7;             // 128 * sum_k wi[col,k]
#pragma unroll
        for (int m = 0; m < 8; ++m) {
            int row0 = brow + wr * 128 + m * 16 + kg * 4;
#pragma unroll
            for (int r = 0; r < 4; ++r) {
                float f = (float)(acc[m][n][r] + rs128) * scale;
                f = f * f;
                f = fminf(f, 6.0f);
                out[(size_t)(row0 + r) * OUT_DIM + col] = f;
            }
        }
    }
}

extern "C" void kernel_launch(void* const* d_in, const int* in_sizes, int n_in,
                              void* d_out, int out_size, void* d_ws, size_t ws_size,
                              hipStream_t stream) {
    const float* x  = (const float*)d_in[0];   // [16384, 2048] f32
    const float* wt = (const float*)d_in[1];   // [256, 256, 8, 8] f32
    float* out = (float*)d_out;                // [16384, 2048] f32

    char* ws = (char*)d_ws;
    int8_t* xq = (int8_t*)ws;                                   // 32 MB
    int8_t* wq = (int8_t*)(ws + (size_t)B_DIM * IN_DIM);        // 4 MB
    int*    rowsum = (int*)(ws + (size_t)B_DIM * IN_DIM
                               + (size_t)OUT_DIM * IN_DIM);     // 8 KB

    hipMemsetAsync(rowsum, 0, OUT_DIM * sizeof(int), stream);
    quant_x_kernel<<<(B_DIM * IN_DIM / 16) / 256, 256, 0, stream>>>(x, xq);
    quant_w_kernel<<<256, 256, 0, stream>>>(wt, wq, rowsum);
    gemm_i8_kernel<<<(B_DIM / BM) * (OUT_DIM / BN), 512, 2 * BUFB, stream>>>(xq, wq, rowsum, out);
}